// Round 9
// baseline (68191.174 us; speedup 1.0000x reference)
//
#include <hip/hip_runtime.h>
#include <math.h>

// Problem constants: B=128, L=512, D_IN=512, D_H=1024, D_OUT=256
#define B_   128
#define L_   512
#define DIN  512
#define DH   1024
#define DOUT 256

#define NBLK 256
#define NTHR 512
#define KC   256      // K-chunk width
#define WLD  260      // padded LDS row stride (floats): 2-way max bank aliasing

typedef float f32x4 __attribute__((ext_vector_type(4)));
typedef unsigned long long u64t;

__device__ __forceinline__ u64t hload2(const float* p) {
  return __hip_atomic_load((const u64t*)p, __ATOMIC_RELAXED, __HIP_MEMORY_SCOPE_AGENT);
}
__device__ __forceinline__ void hstore(float* p, float v) {
  __hip_atomic_store(p, v, __ATOMIC_RELAXED, __HIP_MEMORY_SCOPE_AGENT);
}

// Persistent fused RNN, L2-streamed weights (no register/LDS weight residency).
// Grid 256 x 512; LDS 114 KB -> 1 block/CU, all co-resident.
// Mapping: xg=bid&7 (XCD n-super-group), idx=bid>>3: mg=idx&7 -> m0=mg*16;
//          n0 = xg*128 + (idx>>3)*32.  Per-XCD weight working set = 768 KB (L2-fit).
// Thread: cg=tid&31 (owns col n0+cg), ks=tid>>5 (k-slice, 16 floats per chunk).
// Step l: h_new = tanh(X_l W_in1^T + (l>=2 ? h W_rec1^T : 0) + b_in1), via 6
// double-buffered K-chunks (2 proj + 4 rec), weights+activations staged in LDS.
// h exchanged cross-XCD with agent-scope atomics; per-m-group barrier (32 blocks).
__global__ __launch_bounds__(NTHR, 1) void rnn_persist(
    const float* __restrict__ X, const float* __restrict__ W_in1,
    const float* __restrict__ b_in1, const float* __restrict__ W_rec1,
    const float* __restrict__ W_out, const float* __restrict__ b_out,
    float* __restrict__ hA, float* __restrict__ hB,
    unsigned* __restrict__ bar, float* __restrict__ Y) {
  __shared__ __align__(16) float Wb[2][32 * WLD];  // 65 KB: W chunk [32 n][KC]
  __shared__ __align__(16) float Ab[2][16 * WLD];  // 32.5 KB: A chunk [16 m][KC]
  __shared__ __align__(16) float Red[8 * 512];     // 16 KB

  const int tid = (int)threadIdx.x;
  const int bid = (int)blockIdx.x;
  const int xg  = bid & 7;
  const int idx = bid >> 3;
  const int mg  = idx & 7;
  const int m0  = mg * 16;
  const int n0  = xg * 128 + (idx >> 3) * 32;

  const int cg = tid & 31;
  const int ks = tid >> 5;        // 0..15
  const int wv = tid >> 6;        // 0..7
  const int kb = ks * 16;         // k offset within chunk

  // staging coordinates
  const int wr_r = tid >> 4;            // W row 0..31
  const int wr_k = (tid & 15) << 4;     // W k-offset (16 floats/thread)
  const int ar   = tid >> 5;            // A row 0..15
  const int ak   = (tid & 31) << 3;     // X: 8 floats/thread
  const int ak2  = (tid & 31) << 1;     // h: 2-float base (+j*64)

  const int mo = tid >> 5, no = tid & 31;
  const float bi0 = b_in1[n0 + no];

  unsigned phase = 0;

#pragma unroll 1
  for (int l = 1; l < L_; ++l) {
    const float* hp = (l & 1) ? hB : hA;
    float* hn       = (l & 1) ? hA : hB;
    const int nch = (l == 1) ? 2 : 6;   // l==1: proj only (rec is zeroed)

    // ---- stage chunk 0 (proj: W_in k[0:256), X k[0:256)) into buf 0 ----
    {
      const float* ws = W_in1 + (size_t)(n0 + wr_r) * DIN + wr_k;
      const f32x4 w0 = *(const f32x4*)(ws + 0), w1 = *(const f32x4*)(ws + 4),
                  w2 = *(const f32x4*)(ws + 8), w3 = *(const f32x4*)(ws + 12);
      const float* xs = X + ((size_t)(m0 + ar) * L_ + l) * DIN + ak;
      const f32x4 a0 = *(const f32x4*)(xs + 0), a1 = *(const f32x4*)(xs + 4);
      float* wd = &Wb[0][wr_r * WLD + wr_k];
      *(f32x4*)(wd + 0) = w0; *(f32x4*)(wd + 4) = w1;
      *(f32x4*)(wd + 8) = w2; *(f32x4*)(wd + 12) = w3;
      float* ad = &Ab[0][ar * WLD + ak];
      *(f32x4*)(ad + 0) = a0; *(f32x4*)(ad + 4) = a1;
    }
    __syncthreads();

    float acc[16];
#pragma unroll
    for (int m = 0; m < 16; ++m) acc[m] = 0.f;

#pragma unroll 1
    for (int c = 0; c < nch; ++c) {
      const int p = c & 1;
      // ---- issue next-chunk global loads (latency hides under compute) ----
      f32x4 wn0, wn1, wn2, wn3, an0, an1;
      u64t hr0, hr1, hr2, hr3;
      const int cn = c + 1;
      const bool have_next = cn < nch;
      const bool next_proj = cn < 2;
      if (have_next) {
        const float* ws = next_proj
            ? W_in1 + (size_t)(n0 + wr_r) * DIN + cn * KC + wr_k
            : W_rec1 + (size_t)(n0 + wr_r) * DH + (cn - 2) * KC + wr_k;
        wn0 = *(const f32x4*)(ws + 0); wn1 = *(const f32x4*)(ws + 4);
        wn2 = *(const f32x4*)(ws + 8); wn3 = *(const f32x4*)(ws + 12);
        if (next_proj) {
          const float* xs = X + ((size_t)(m0 + ar) * L_ + l) * DIN + cn * KC + ak;
          an0 = *(const f32x4*)(xs + 0); an1 = *(const f32x4*)(xs + 4);
        } else {
          const float* hs = hp + (size_t)(m0 + ar) * DH + (cn - 2) * KC + ak2;
          hr0 = hload2(hs + 0);   hr1 = hload2(hs + 64);
          hr2 = hload2(hs + 128); hr3 = hload2(hs + 192);
        }
      }
      // ---- compute chunk c: acc[m] += A[m][kb..kb+16) . W[cg][kb..kb+16) ----
      {
        const float* wb = &Wb[p][cg * WLD + kb];
        const f32x4 w0 = *(const f32x4*)(wb + 0), w1 = *(const f32x4*)(wb + 4),
                    w2 = *(const f32x4*)(wb + 8), w3 = *(const f32x4*)(wb + 12);
#pragma unroll
        for (int m = 0; m < 16; ++m) {
          const float* ab = &Ab[p][m * WLD + kb];
          const f32x4 a0 = *(const f32x4*)(ab + 0), a1 = *(const f32x4*)(ab + 4),
                      a2 = *(const f32x4*)(ab + 8), a3 = *(const f32x4*)(ab + 12);
          f32x4 sv = a0 * w0;
          sv += a1 * w1; sv += a2 * w2; sv += a3 * w3;
          acc[m] += (sv[0] + sv[1]) + (sv[2] + sv[3]);
        }
      }
      // ---- publish next chunk to the other buffer ----
      if (have_next) {
        const int pn = p ^ 1;
        float* wd = &Wb[pn][wr_r * WLD + wr_k];
        *(f32x4*)(wd + 0) = wn0; *(f32x4*)(wd + 4) = wn1;
        *(f32x4*)(wd + 8) = wn2; *(f32x4*)(wd + 12) = wn3;
        if (next_proj) {
          float* ad = &Ab[pn][ar * WLD + ak];
          *(f32x4*)(ad + 0) = an0; *(f32x4*)(ad + 4) = an1;
        } else {
          float* ad = &Ab[pn][ar * WLD + ak2];
          union { u64t u; float2 f; } cv;
          cv.u = hr0; *(float2*)(ad + 0)   = cv.f;
          cv.u = hr1; *(float2*)(ad + 64)  = cv.f;
          cv.u = hr2; *(float2*)(ad + 128) = cv.f;
          cv.u = hr3; *(float2*)(ad + 192) = cv.f;
        }
      }
      __syncthreads();
    }

    // ---- reduce 16 k-slices: in-wave pair, then 8 partials via Red ----
#pragma unroll
    for (int m = 0; m < 16; ++m) acc[m] += __shfl_xor(acc[m], 32);
    if ((tid & 32) == 0) {
#pragma unroll
      for (int m = 0; m < 16; ++m) Red[wv * 512 + m * 32 + cg] = acc[m];
    }
    __syncthreads();
    // ---- finalize 1 output/thread: sum 8 partials, bias, tanh, store ----
    {
      float s = 0.f;
#pragma unroll
      for (int w = 0; w < 8; ++w) s += Red[w * 512 + mo * 32 + no];
      hstore(hn + (size_t)(m0 + mo) * DH + n0 + no, tanhf(s + bi0));
    }
    // ---- per-m-group barrier (the 32 blocks sharing m-tile mg) ----
    __threadfence();
    __syncthreads();
    ++phase;
    if (tid == 0) {
      unsigned* ctr = bar + (size_t)mg * 32;  // 128 B apart
      __hip_atomic_fetch_add(ctr, 1u, __ATOMIC_ACQ_REL, __HIP_MEMORY_SCOPE_AGENT);
      const unsigned tgt = phase * 32u;
      while (__hip_atomic_load(ctr, __ATOMIC_ACQUIRE, __HIP_MEMORY_SCOPE_AGENT) < tgt)
        __builtin_amdgcn_s_sleep(1);
    }
    __syncthreads();
  }

  // ---- output layer: Y = tanh(h_final @ W_out^T + b_out); h_final = hA ----
  if (n0 < DOUT) {   // xg 0..1: 64 blocks cover (8 m-tiles x 8 out n-tiles)
    // stage chunk 0 (W_out k[0:256), h k[0:256))
    {
      const float* ws = W_out + (size_t)(n0 + wr_r) * DH + wr_k;
      const f32x4 w0 = *(const f32x4*)(ws + 0), w1 = *(const f32x4*)(ws + 4),
                  w2 = *(const f32x4*)(ws + 8), w3 = *(const f32x4*)(ws + 12);
      const float* hs = hA + (size_t)(m0 + ar) * DH + ak2;
      u64t h0 = hload2(hs + 0), h1 = hload2(hs + 64),
           h2 = hload2(hs + 128), h3 = hload2(hs + 192);
      float* wd = &Wb[0][wr_r * WLD + wr_k];
      *(f32x4*)(wd + 0) = w0; *(f32x4*)(wd + 4) = w1;
      *(f32x4*)(wd + 8) = w2; *(f32x4*)(wd + 12) = w3;
      float* ad = &Ab[0][ar * WLD + ak2];
      union { u64t u; float2 f; } cv;
      cv.u = h0; *(float2*)(ad + 0)   = cv.f;
      cv.u = h1; *(float2*)(ad + 64)  = cv.f;
      cv.u = h2; *(float2*)(ad + 128) = cv.f;
      cv.u = h3; *(float2*)(ad + 192) = cv.f;
    }
    __syncthreads();
    float acc[16];
#pragma unroll
    for (int m = 0; m < 16; ++m) acc[m] = 0.f;
#pragma unroll 1
    for (int c = 0; c < 4; ++c) {
      const int p = c & 1;
      f32x4 wn0, wn1, wn2, wn3;
      u64t hr0, hr1, hr2, hr3;
      const bool have_next = c < 3;
      if (have_next) {
        const float* ws = W_out + (size_t)(n0 + wr_r) * DH + (c + 1) * KC + wr_k;
        wn0 = *(const f32x4*)(ws + 0); wn1 = *(const f32x4*)(ws + 4);
        wn2 = *(const f32x4*)(ws + 8); wn3 = *(const f32x4*)(ws + 12);
        const float* hs = hA + (size_t)(m0 + ar) * DH + (c + 1) * KC + ak2;
        hr0 = hload2(hs + 0);   hr1 = hload2(hs + 64);
        hr2 = hload2(hs + 128); hr3 = hload2(hs + 192);
      }
      {
        const float* wb = &Wb[p][cg * WLD + kb];
        const f32x4 w0 = *(const f32x4*)(wb + 0), w1 = *(const f32x4*)(wb + 4),
                    w2 = *(const f32x4*)(wb + 8), w3 = *(const f32x4*)(wb + 12);
#pragma unroll
        for (int m = 0; m < 16; ++m) {
          const float* ab = &Ab[p][m * WLD + kb];
          const f32x4 a0 = *(const f32x4*)(ab + 0), a1 = *(const f32x4*)(ab + 4),
                      a2 = *(const f32x4*)(ab + 8), a3 = *(const f32x4*)(ab + 12);
          f32x4 sv = a0 * w0;
          sv += a1 * w1; sv += a2 * w2; sv += a3 * w3;
          acc[m] += (sv[0] + sv[1]) + (sv[2] + sv[3]);
        }
      }
      if (have_next) {
        const int pn = p ^ 1;
        float* wd = &Wb[pn][wr_r * WLD + wr_k];
        *(f32x4*)(wd + 0) = wn0; *(f32x4*)(wd + 4) = wn1;
        *(f32x4*)(wd + 8) = wn2; *(f32x4*)(wd + 12) = wn3;
        float* ad = &Ab[pn][ar * WLD + ak2];
        union { u64t u; float2 f; } cv;
        cv.u = hr0; *(float2*)(ad + 0)   = cv.f;
        cv.u = hr1; *(float2*)(ad + 64)  = cv.f;
        cv.u = hr2; *(float2*)(ad + 128) = cv.f;
        cv.u = hr3; *(float2*)(ad + 192) = cv.f;
      }
      __syncthreads();
    }
#pragma unroll
    for (int m = 0; m < 16; ++m) acc[m] += __shfl_xor(acc[m], 32);
    if ((tid & 32) == 0) {
#pragma unroll
      for (int m = 0; m < 16; ++m) Red[wv * 512 + m * 32 + cg] = acc[m];
    }
    __syncthreads();
    {
      float s = 0.f;
#pragma unroll
      for (int w = 0; w < 8; ++w) s += Red[w * 512 + mo * 32 + no];
      Y[(size_t)(m0 + mo) * DOUT + n0 + no] = tanhf(s + b_out[n0 + no]);
    }
  }
}

extern "C" void kernel_launch(void* const* d_in, const int* in_sizes, int n_in,
                              void* d_out, int out_size, void* d_ws, size_t ws_size,
                              hipStream_t stream) {
  const float* X      = (const float*)d_in[0];
  const float* W_in1  = (const float*)d_in[1];
  const float* b_in1  = (const float*)d_in[2];
  const float* W_rec1 = (const float*)d_in[3];
  // d_in[4..6] = W_in2/b_in2/W_rec2 : dead code w.r.t. Y
  const float* W_out  = (const float*)d_in[7];
  const float* b_out  = (const float*)d_in[8];
  float* out = (float*)d_out;

  // ws layout: [0,4096): 8 group-barrier counters (128 B apart); then hA, hB
  unsigned* bar = (unsigned*)d_ws;
  float* hA = (float*)((char*)d_ws + 4096);
  float* hB = hA + (size_t)B_ * DH;

  hipMemsetAsync(d_ws, 0, 4096, stream);  // reset barriers each launch (replay-safe)
  rnn_persist<<<NBLK, NTHR, 0, stream>>>(X, W_in1, b_in1, W_rec1, W_out, b_out,
                                         hA, hB, bar, out);
}